// Round 12
// baseline (285.959 us; speedup 1.0000x reference)
//
#include <hip/hip_runtime.h>
#include <math.h>

#define B  128
#define L  64
#define NS 32
#define NI 16
#define D  256

typedef __attribute__((ext_vector_type(8))) short bf16x8;
typedef __attribute__((ext_vector_type(4))) float f32x4;

__device__ __forceinline__ float wave_reduce_sum(float v) {
#pragma unroll
  for (int off = 32; off; off >>= 1) v += __shfl_xor(v, off, 64);
  return v;
}
__device__ __forceinline__ float wave_reduce_max(float v) {
#pragma unroll
  for (int off = 32; off; off >>= 1) v = fmaxf(v, __shfl_xor(v, off, 64));
  return v;
}

// packed RTNE f32x2 -> bf16x2 (single HW instr)
__device__ __forceinline__ uint cvt_pk_bf16(float a, float b) {
  uint r;
  asm("v_cvt_pk_bf16_f32 %0, %1, %2" : "=v"(r) : "v"(a), "v"(b));
  return r;  // lo16 = bf16(a), hi16 = bf16(b)
}
// float4 -> hi-pair u32x2 + lo-pair u32x2 (x ~= hi + lo, residual ~2^-17)
__device__ __forceinline__ void split4(float4 v, uint2& h, uint2& lo) {
  h.x = cvt_pk_bf16(v.x, v.y);
  h.y = cvt_pk_bf16(v.z, v.w);
  float h0 = __uint_as_float(h.x << 16);
  float h1 = __uint_as_float(h.x & 0xFFFF0000u);
  float h2 = __uint_as_float(h.y << 16);
  float h3 = __uint_as_float(h.y & 0xFFFF0000u);
  lo.x = cvt_pk_bf16(v.x - h0, v.y - h1);
  lo.y = cvt_pk_bf16(v.z - h2, v.w - h3);
}

// async global->LDS DMA, 16B/lane; LDS dest = wave-uniform base + lane*16,
// global src = per-lane pointer.
__device__ __forceinline__ void dma16(const void* g, void* l) {
  __builtin_amdgcn_global_load_lds(
      (const __attribute__((address_space(1))) void*)g,
      (__attribute__((address_space(3))) void*)l, 16, 0, 0);
}

// ---------------------------------------------------------------------------
// KX: pre-split tf into bf16 hi/lo images, tiled [128 b][64 k] per (l,kq),
// 128B rows of 8 16B-units, unit ^= (row&7)  ->  k3's DMA is a linear copy
// and the ds_read_b128 fragment reads are bank-conflict-free.
// ---------------------------------------------------------------------------
__global__ __launch_bounds__(256) void kx_split(
    const float* __restrict__ tf, ushort* __restrict__ xh,
    ushort* __restrict__ xl) {
  int tile = blockIdx.x;          // l*4 + kq
  int l = tile >> 2, kq = tile & 3;
  int t = threadIdx.x;
  int row = t >> 1, half = t & 1;
  const float* src = tf + ((size_t)row * L + l) * D + kq * 64 + half * 32;
  ushort* ht = xh + (size_t)tile * 8192 + row * 64;
  ushort* lt = xl + (size_t)tile * 8192 + row * 64;
#pragma unroll
  for (int u = 0; u < 4; ++u) {
    float4 v0 = *(const float4*)(src + u * 8);
    float4 v1 = *(const float4*)(src + u * 8 + 4);
    uint2 h0, e0, h1, e1;
    split4(v0, h0, e0);
    split4(v1, h1, e1);
    int gu = (half * 4 + u) ^ (row & 7);
    uint4 hu = {h0.x, h0.y, h1.x, h1.y};
    uint4 lu = {e0.x, e0.y, e1.x, e1.y};
    *(uint4*)&ht[gu * 8] = hu;
    *(uint4*)&lt[gu * 8] = lu;
  }
}

// ---------------------------------------------------------------------------
// K1: per (b,l): a_words = mean(x); logits = w_route_ws[l] . x; softmax;
//     wlsT[l][s][b] = c_ws * a_words.
// ---------------------------------------------------------------------------
__global__ __launch_bounds__(256) void k1_route_words(
    const float* __restrict__ tf, const float* __restrict__ wr,
    float* __restrict__ wlsT, float* __restrict__ a_words) {
  int bl = blockIdx.x;
  int b  = bl >> 6;
  int l  = bl & (L - 1);
  int t  = threadIdx.x;
  int wave = t >> 6, lane = t & 63;
  __shared__ float sx[D];
  __shared__ float slog[NS];
  __shared__ float s_aw;
  sx[t] = tf[bl * D + t];
  __syncthreads();
  const float* wbase = wr + l * NS * D;
#pragma unroll
  for (int r = 0; r < 8; ++r) {
    int n = wave * 8 + r;
    const float* w = wbase + n * D;
    float p = 0.f;
#pragma unroll
    for (int jj = 0; jj < 4; ++jj) {
      int j = lane + jj * 64;
      p = fmaf(w[j], sx[j], p);
    }
    p = wave_reduce_sum(p);
    if (lane == 0) slog[n] = p;
  }
  if (wave == 0) {
    float p = sx[lane] + sx[lane + 64] + sx[lane + 128] + sx[lane + 192];
    p = wave_reduce_sum(p);
    if (lane == 0) s_aw = p * (1.f / D);
  }
  __syncthreads();
  if (wave == 0) {
    float aw = s_aw;
    float v = (lane < NS) ? slog[lane] : -INFINITY;
    float m = wave_reduce_max(v);
    float e = (lane < NS) ? __expf(v - m) : 0.f;
    float s = wave_reduce_sum(e);
    if (lane < NS) wlsT[(l * NS + lane) * B + b] = (e / s) * aw;
    if (lane == 0) a_words[bl] = aw;
  }
}

// ---------------------------------------------------------------------------
// K2: weighted_c[b,s] = sum_l wlsT[l][s][b]; a_slots = wc / sum_l a_words.
// ---------------------------------------------------------------------------
__global__ __launch_bounds__(64) void k2_slots_agg(
    const float* __restrict__ wlsT, const float* __restrict__ a_words,
    float* __restrict__ weighted_c, float* __restrict__ a_slots) {
  int b = blockIdx.x;
  int lane = threadIdx.x;
  float aw = a_words[b * L + lane];
  float sa = wave_reduce_sum(aw);
  if (lane < NS) {
    float wc = 0.f;
    for (int l = 0; l < L; ++l) wc += wlsT[(l * NS + lane) * B + b];
    weighted_c[b * NS + lane] = wc;
    a_slots[b * NS + lane] = wc / sa;
  }
}

// ---------------------------------------------------------------------------
// K3 v8: 3-term emulated-fp32 GEMM (round-10-verified numerics) with
// 256B-contiguous W DMA chunks (K-step 64) and depth-2 counted vmcnt.
// Block (sp, s, ihalf) = 128 b x 128 i; 4 waves = b-quarters (32 b x 128 i).
// Step (l, kq in 4, ic in 4): W chunk = 32 i-rows x 64 k f32 (256B/row
// contiguous), 4-deep LDS ring; A = hi/lo pre-split images, [128][64]
// single-buffered, reloaded at kq tails.  Uniform 2 W-DMA/wave/step ->
// "vmcnt(4)" keeps 2 steps in flight, never drains to 0.
// Terms: Ah*Wh + Ah*Wl + Al*Wh; per-l scale fold in fp32 (R += sw[b]*P).
// ---------------------------------------------------------------------------
__global__ __launch_bounds__(256, 2) void k3_mfma(
    const ushort* __restrict__ xh, const ushort* __restrict__ xl,
    const float* __restrict__ wp, const float* __restrict__ wlsT,
    float* __restrict__ part, int nsplit) {
  __shared__ ushort Ah[8192], Al[8192];  // 16KB each: [128 b][64 k] swz
  __shared__ float  Wt[4][2048];         // 4 x 8KB ring: [32 r][64 k] swz
  __shared__ float  swb[2][256];         // 2 x 1KB wls scales

  int bx  = blockIdx.x;
  int sp  = bx & (nsplit - 1);   // bx%nsplit -> same-sp on same XCD
  int rem = bx / nsplit;
  int ih  = rem & 1, s = rem >> 1;
  int i0  = ih * 128;
  int lchunk = L / nsplit, l0 = sp * lchunk;
  int steps  = lchunk * 16;      // (kq 4) x (ic 4) per l

  int t = threadIdx.x, lane = t & 63, wv = t >> 6;
  int fr = lane & 15, q = lane >> 4;

  f32x4 P[2][8], R[2][8];
#pragma unroll
  for (int mi = 0; mi < 2; ++mi)
#pragma unroll
    for (int n = 0; n < 8; ++n) { P[mi][n] = (f32x4)0.f; R[mi][n] = (f32x4)0.f; }

  auto issueW = [&](int n) {     // exactly 2 DMA per wave
    int pb = n & 3;              // ring slot from UNCLAMPED index
    int cs = n < steps ? n : steps - 1;
    int li = cs >> 4, kq = (cs >> 2) & 3, ic = cs & 3;
    int l  = l0 + li;
    const char* base = (const char*)wp +
        (((size_t)l * NS + s) * (D * D) + (size_t)(i0 + ic * 32) * D + kq * 64) * 4;
    int r4 = lane >> 4, v = lane & 15;
#pragma unroll
    for (int wi = 0; wi < 2; ++wi) {
      int rb = wv * 8 + wi * 4;                // local rows [rb, rb+4)
      const char* src = base + (size_t)(rb + r4) * 1024 +
                        ((v ^ ((rb + r4) & 7)) << 4);
      dma16(src, (char*)&Wt[pb][0] + rb * 256);
    }
  };
  auto issueA = [&](int li, int kq) {          // 8 DMA per wave (32KB)
    size_t tile = ((size_t)(l0 + li) * 4 + kq) * 8192;
#pragma unroll
    for (int c = 0; c < 4; ++c) {
      dma16(xh + tile + wv * 2048 + c * 512 + lane * 8, &Ah[wv * 2048 + c * 512]);
      dma16(xl + tile + wv * 2048 + c * 512 + lane * 8, &Al[wv * 2048 + c * 512]);
    }
  };
  auto issueSW = [&](int li) {                 // 1 DMA per wave
    const char* src = (const char*)(wlsT + ((size_t)(l0 + li) * NS + s) * B);
    dma16(src + lane * 16, &swb[li & 1][0]);
  };

  issueA(0, 0);
  issueSW(0);
  issueW(0);
  issueW(1);

  int ngroups = steps >> 2;      // one group = one (l,kq), 4 ic-steps
  for (int g = 0; g < ngroups; ++g) {
#pragma unroll
    for (int ic = 0; ic < 4; ++ic) {
      int st = g * 4 + ic;
      issueW(st + 2);
      asm volatile("s_waitcnt vmcnt(4)" ::: "memory");  // st ready; st+1/st+2 in flight
      __builtin_amdgcn_s_barrier();
      int pb = st & 3;
      // ---- W fragments: LDS f32 (swizzled) -> regs -> hi/lo bf16 ----
      bf16x8 wh[2][2], wl[2][2];
#pragma unroll
      for (int ni = 0; ni < 2; ++ni) {
        int r = ni * 16 + fr;
        const char* rbp = (const char*)&Wt[pb][0] + r * 256;
        int key = r & 7;
#pragma unroll
        for (int k2 = 0; k2 < 2; ++k2) {
          float4 w0 = *(const float4*)(rbp + (((k2 * 8 + q * 2 + 0) ^ key) << 4));
          float4 w1 = *(const float4*)(rbp + (((k2 * 8 + q * 2 + 1) ^ key) << 4));
          uint2 h0, e0, h1, e1;
          split4(w0, h0, e0);
          split4(w1, h1, e1);
          uint4 hu = {h0.x, h0.y, h1.x, h1.y};
          uint4 lu = {e0.x, e0.y, e1.x, e1.y};
          wh[ni][k2] = __builtin_bit_cast(bf16x8, hu);
          wl[ni][k2] = __builtin_bit_cast(bf16x8, lu);
        }
      }
      // ---- MFMA: 3-term, statically-indexed accumulators ----
#pragma unroll
      for (int k2 = 0; k2 < 2; ++k2) {
#pragma unroll
        for (int mi = 0; mi < 2; ++mi) {
          int ar = wv * 32 + mi * 16 + fr;
          int au = ar * 64 + (((k2 * 4 + q) ^ (ar & 7)) << 3);
          bf16x8 ah = *(const bf16x8*)&Ah[au];
          bf16x8 al = *(const bf16x8*)&Al[au];
#pragma unroll
          for (int ni = 0; ni < 2; ++ni) {
            P[mi][ic * 2 + ni] = __builtin_amdgcn_mfma_f32_16x16x32_bf16(
                ah, wh[ni][k2], P[mi][ic * 2 + ni], 0, 0, 0);
            P[mi][ic * 2 + ni] = __builtin_amdgcn_mfma_f32_16x16x32_bf16(
                ah, wl[ni][k2], P[mi][ic * 2 + ni], 0, 0, 0);
            P[mi][ic * 2 + ni] = __builtin_amdgcn_mfma_f32_16x16x32_bf16(
                al, wh[ni][k2], P[mi][ic * 2 + ni], 0, 0, 0);
          }
        }
      }
      asm volatile("s_waitcnt lgkmcnt(0)" ::: "memory");  // LDS reads done
      __builtin_amdgcn_s_barrier();                       // before overwrite
    }
    // ---- group tail ----
    int li = g >> 2, kq = g & 3;
    if (kq == 3) {
      // end of l: fold R += sw[b]*P (fp32); swb[li&1] still valid
#pragma unroll
      for (int mi = 0; mi < 2; ++mi) {
        f32x4 s4 = *(const f32x4*)&swb[li & 1][wv * 32 + mi * 16 + q * 4];
#pragma unroll
        for (int n = 0; n < 8; ++n) {
          R[mi][n] += s4 * P[mi][n];
          P[mi][n] = (f32x4)0.f;
        }
      }
      if (li + 1 < lchunk) {
        issueA(li + 1, 0);
        issueSW(li + 1);
      }
    } else {
      issueA(li, kq + 1);
    }
  }

  // ---- epilogue: write partials ----
  float* pout = part + ((size_t)sp * NS + s) * (B * D);
#pragma unroll
  for (int mi = 0; mi < 2; ++mi)
#pragma unroll
    for (int n = 0; n < 8; ++n) {
      int col = i0 + n * 16 + fr;
#pragma unroll
      for (int e = 0; e < 4; ++e) {
        int bb = wv * 32 + mi * 16 + q * 4 + e;
        pout[(size_t)bb * D + col] = R[mi][n][e];
      }
    }
}

// ---------------------------------------------------------------------------
// K3R: u_slots[b,s,i] = (sum_sp part[sp,s,b,i]) / weighted_c[b,s]
// ---------------------------------------------------------------------------
__global__ __launch_bounds__(256) void k3r_reduce(
    const float* __restrict__ part, const float* __restrict__ wc,
    float* __restrict__ u_slots, int nsplit) {
  int idx = blockIdx.x * 256 + threadIdx.x;  // over (s,b,i)
  int i  = idx & (D - 1);
  int sb = idx >> 8;
  int b  = sb & (B - 1);
  int s  = sb >> 7;
  float v = 0.f;
  for (int sp = 0; sp < nsplit; ++sp)
    v += part[(size_t)sp * (NS * B * D) + idx];
  u_slots[((size_t)b * NS + s) * D + i] = v / wc[b * NS + s];
}

// ---------------------------------------------------------------------------
// K4: per (b,s): logits2 = w_route_si[s] . u_slots[b,s]; softmax over NI;
//     w2 = c_si * a_slots.
// ---------------------------------------------------------------------------
__global__ __launch_bounds__(64) void k4_route_si(
    const float* __restrict__ u_slots, const float* __restrict__ wr_si,
    const float* __restrict__ a_slots, float* __restrict__ w2) {
  int bs = blockIdx.x;
  int s  = bs & (NS - 1);
  int lane = threadIdx.x;
  __shared__ float su[D];
  __shared__ float slog[NI];
#pragma unroll
  for (int jj = 0; jj < 4; ++jj) su[lane + jj * 64] = u_slots[bs * D + lane + jj * 64];
  __syncthreads();
  for (int i = 0; i < NI; ++i) {
    const float* w = wr_si + (s * NI + i) * D;
    float p = 0.f;
#pragma unroll
    for (int jj = 0; jj < 4; ++jj) {
      int j = lane + jj * 64;
      p = fmaf(w[j], su[j], p);
    }
    p = wave_reduce_sum(p);
    if (lane == 0) slog[i] = p;
  }
  __syncthreads();
  float v = (lane < NI) ? slog[lane] : -INFINITY;
  float m = wave_reduce_max(v);
  float e = (lane < NI) ? __expf(v - m) : 0.f;
  float ssum = wave_reduce_sum(e);
  if (lane < NI) w2[bs * NI + lane] = (e / ssum) * a_slots[bs];
}

// ---------------------------------------------------------------------------
// K5: wc2[b,i] = sum_s w2; a_intents = wc2 / sum_s a_slots.
// ---------------------------------------------------------------------------
__global__ __launch_bounds__(64) void k5_intents_agg(
    const float* __restrict__ w2, const float* __restrict__ a_slots,
    float* __restrict__ wc2, float* __restrict__ a_intents) {
  int b = blockIdx.x;
  int lane = threadIdx.x;
  float as = (lane < NS) ? a_slots[b * NS + lane] : 0.f;
  float sas = wave_reduce_sum(as);
  if (lane < NI) {
    float wc = 0.f;
    for (int s = 0; s < NS; ++s) wc += w2[(b * NS + s) * NI + lane];
    wc2[b * NI + lane] = wc;
    a_intents[b * NI + lane] = wc / sas;
  }
}

// ---------------------------------------------------------------------------
// K6: Wsum[s,i,k] = sum_j w_pose_si[s,i,j,k] (float4-vectorized over k).
// ---------------------------------------------------------------------------
__global__ __launch_bounds__(256) void k6_wsum(
    const float* __restrict__ wps, float* __restrict__ wsum) {
  __shared__ float red[4][D];
  int si = blockIdx.x;
  int t  = threadIdx.x;
  int k4 = (t & 63) * 4;
  int jg = t >> 6;
  const float* base = wps + (size_t)si * D * D;
  float4 acc = {0.f, 0.f, 0.f, 0.f};
  for (int j = jg; j < D; j += 4) {
    float4 v = *(const float4*)(base + (size_t)j * D + k4);
    acc.x += v.x; acc.y += v.y; acc.z += v.z; acc.w += v.w;
  }
  *(float4*)&red[jg][k4] = acc;
  __syncthreads();
  wsum[si * D + t] = (red[0][t] + red[1][t]) + (red[2][t] + red[3][t]);
}

// ---------------------------------------------------------------------------
// K7: u_intents[b,i,k] = sum_s w2[b,s,i]*u_slots[b,s,k]*Wsum[s,i,k] / wc2[b,i]
// ---------------------------------------------------------------------------
__global__ __launch_bounds__(256) void k7_uintents(
    const float* __restrict__ u_slots, const float* __restrict__ w2,
    const float* __restrict__ wsum, const float* __restrict__ wc2,
    float* __restrict__ u_intents) {
  int bi = blockIdx.x;
  int b = bi >> 4, i = bi & (NI - 1);
  int k = threadIdx.x;
  float acc = 0.f;
  for (int s = 0; s < NS; ++s) {
    float w = w2[(b * NS + s) * NI + i];
    acc = fmaf(w * u_slots[(b * NS + s) * D + k], wsum[(s * NI + i) * D + k], acc);
  }
  u_intents[bi * D + k] = acc / wc2[bi];
}

// ---------------------------------------------------------------------------
extern "C" void kernel_launch(void* const* d_in, const int* in_sizes, int n_in,
                              void* d_out, int out_size, void* d_ws, size_t ws_size,
                              hipStream_t stream) {
  const float* tf    = (const float*)d_in[0];  // (B,L,D)
  const float* wr_ws = (const float*)d_in[1];  // (L,NS,D)
  const float* wp_ws = (const float*)d_in[2];  // (L,NS,D,D)
  const float* wr_si = (const float*)d_in[3];  // (NS,NI,D)
  const float* wp_si = (const float*)d_in[4];  // (NS,NI,D,D)

  float* out       = (float*)d_out;
  float* a_slots   = out;                      // B*NS
  float* u_slots   = a_slots + B * NS;         // B*NS*D
  float* a_intents = u_slots + B * NS * D;     // B*NI
  float* u_intents = a_intents + B * NI;       // B*NI*D

  float* ws         = (float*)d_ws;
  float* wlsT       = ws;                      // L*NS*B  = 262144
  float* a_words    = wlsT + L * NS * B;       // B*L     = 8192
  float* weighted_c = a_words + B * L;         // B*NS    = 4096
  float* w2         = weighted_c + B * NS;     // B*NS*NI = 65536
  float* wc2        = w2 + B * NS * NI;        // B*NI    = 2048
  float* wsum       = wc2 + B * NI;            // NS*NI*D = 131072
  // bf16 hi/lo swizzled images of tf: 256 tiles x 8192 ushorts each
  ushort* xh        = (ushort*)(wsum + NS * NI * D);       // 2,097,152 ushorts
  ushort* xl        = xh + (size_t)L * 4 * 8192;           // 2,097,152 ushorts
  float*  part      = (float*)(xl + (size_t)L * 4 * 8192); // nsplit*NS*B*D

  const size_t base_f  = 473088 + 2097152;     // floats incl. images
  const size_t chunk_f = (size_t)NS * B * D;   // 1,048,576 per split
  size_t avail_f = ws_size / sizeof(float);
  int nsplit = 1;
  if (avail_f >= base_f + 8 * chunk_f)      nsplit = 8;
  else if (avail_f >= base_f + 4 * chunk_f) nsplit = 4;
  else if (avail_f >= base_f + 2 * chunk_f) nsplit = 2;

  kx_split<<<L * 4, 256, 0, stream>>>(tf, xh, xl);
  k1_route_words<<<B * L, 256, 0, stream>>>(tf, wr_ws, wlsT, a_words);
  k2_slots_agg<<<B, 64, 0, stream>>>(wlsT, a_words, weighted_c, a_slots);
  // grid: (s x ihalf) x nsplit; bx%nsplit = sp -> same-sp on same XCD
  k3_mfma<<<NS * 2 * nsplit, 256, 0, stream>>>(xh, xl, wp_ws, wlsT, part, nsplit);
  k3r_reduce<<<(NS * B * D) / 256, 256, 0, stream>>>(part, weighted_c, u_slots, nsplit);
  k6_wsum<<<NS * NI, 256, 0, stream>>>(wp_si, wsum);
  k4_route_si<<<B * NS, 64, 0, stream>>>(u_slots, wr_si, a_slots, w2);
  k5_intents_agg<<<B, 64, 0, stream>>>(w2, a_slots, wc2, a_intents);
  k7_uintents<<<B * NI, 256, 0, stream>>>(u_slots, w2, wsum, wc2, u_intents);
}

// Round 14
// 251.147 us; speedup vs baseline: 1.1386x; 1.1386x over previous
//
#include <hip/hip_runtime.h>
#include <math.h>

#define B  128
#define L  64
#define NS 32
#define NI 16
#define D  256

typedef __attribute__((ext_vector_type(8))) short bf16x8;
typedef __attribute__((ext_vector_type(4))) float f32x4;
typedef __attribute__((ext_vector_type(16))) float f32x16;

__device__ __forceinline__ float wave_reduce_sum(float v) {
#pragma unroll
  for (int off = 32; off; off >>= 1) v += __shfl_xor(v, off, 64);
  return v;
}
__device__ __forceinline__ float wave_reduce_max(float v) {
#pragma unroll
  for (int off = 32; off; off >>= 1) v = fmaxf(v, __shfl_xor(v, off, 64));
  return v;
}

// packed RTNE f32x2 -> bf16x2 (single HW instr)
__device__ __forceinline__ uint cvt_pk_bf16(float a, float b) {
  uint r;
  asm("v_cvt_pk_bf16_f32 %0, %1, %2" : "=v"(r) : "v"(a), "v"(b));
  return r;  // lo16 = bf16(a), hi16 = bf16(b)
}
// float4 -> hi-pair u32x2 + lo-pair u32x2 (x ~= hi + lo, residual ~2^-17)
__device__ __forceinline__ void split4(float4 v, uint2& h, uint2& lo) {
  h.x = cvt_pk_bf16(v.x, v.y);
  h.y = cvt_pk_bf16(v.z, v.w);
  float h0 = __uint_as_float(h.x << 16);
  float h1 = __uint_as_float(h.x & 0xFFFF0000u);
  float h2 = __uint_as_float(h.y << 16);
  float h3 = __uint_as_float(h.y & 0xFFFF0000u);
  lo.x = cvt_pk_bf16(v.x - h0, v.y - h1);
  lo.y = cvt_pk_bf16(v.z - h2, v.w - h3);
}

// async global->LDS DMA, 16B/lane; LDS dest = wave-uniform base + lane*16,
// global src = per-lane pointer.
__device__ __forceinline__ void dma16(const void* g, void* l) {
  __builtin_amdgcn_global_load_lds(
      (const __attribute__((address_space(1))) void*)g,
      (__attribute__((address_space(3))) void*)l, 16, 0, 0);
}

// ---------------------------------------------------------------------------
// KX: pre-split tf into bf16 hi/lo images, tiled [128 b][32 k] per (l, jci
// in 8), 64B rows of 4 16B-units, unit ^= ((row>>1)&3).
// Bank math: 16-lane cohort reads rows r..r+15 at one unit -> bank quad =
// (row&1)*16 + ((u^key)*4): 8 distinct quads over 8 rows -> 2-way = free.
// (Round 10's (row&3) key gave 4-way: rows 0/4/8/12 collided.)
// ---------------------------------------------------------------------------
__global__ __launch_bounds__(256) void kx_split(
    const float* __restrict__ tf, ushort* __restrict__ xh,
    ushort* __restrict__ xl) {
  int bx = blockIdx.x;            // l*4 + jp   (jp = 64-col pair)
  int l  = bx >> 2, jp = bx & 3;
  int t  = threadIdx.x;
  int row = t >> 1, sub = t & 1;
  int tile = bx * 2 + sub;        // l*8 + jci
  const float* src = tf + ((size_t)row * L + l) * D + (jp * 2 + sub) * 32;
  ushort* ht = xh + (size_t)tile * 4096 + row * 32;
  ushort* lt = xl + (size_t)tile * 4096 + row * 32;
  int key = (row >> 1) & 3;
#pragma unroll
  for (int u = 0; u < 4; ++u) {
    float4 v0 = *(const float4*)(src + u * 8);
    float4 v1 = *(const float4*)(src + u * 8 + 4);
    uint2 h0, e0, h1, e1;
    split4(v0, h0, e0);
    split4(v1, h1, e1);
    int up = (u ^ key) * 8;
    uint4 hu = {h0.x, h0.y, h1.x, h1.y};
    uint4 lu = {e0.x, e0.y, e1.x, e1.y};
    *(uint4*)&ht[up] = hu;
    *(uint4*)&lt[up] = lu;
  }
}

// ---------------------------------------------------------------------------
// K1: per (b,l): a_words = mean(x); logits = w_route_ws[l] . x; softmax;
//     wlsT[l][s][b] = c_ws * a_words.
// ---------------------------------------------------------------------------
__global__ __launch_bounds__(256) void k1_route_words(
    const float* __restrict__ tf, const float* __restrict__ wr,
    float* __restrict__ wlsT, float* __restrict__ a_words) {
  int bl = blockIdx.x;
  int b  = bl >> 6;
  int l  = bl & (L - 1);
  int t  = threadIdx.x;
  int wave = t >> 6, lane = t & 63;
  __shared__ float sx[D];
  __shared__ float slog[NS];
  __shared__ float s_aw;
  sx[t] = tf[bl * D + t];
  __syncthreads();
  const float* wbase = wr + l * NS * D;
#pragma unroll
  for (int r = 0; r < 8; ++r) {
    int n = wave * 8 + r;
    const float* w = wbase + n * D;
    float p = 0.f;
#pragma unroll
    for (int jj = 0; jj < 4; ++jj) {
      int j = lane + jj * 64;
      p = fmaf(w[j], sx[j], p);
    }
    p = wave_reduce_sum(p);
    if (lane == 0) slog[n] = p;
  }
  if (wave == 0) {
    float p = sx[lane] + sx[lane + 64] + sx[lane + 128] + sx[lane + 192];
    p = wave_reduce_sum(p);
    if (lane == 0) s_aw = p * (1.f / D);
  }
  __syncthreads();
  if (wave == 0) {
    float aw = s_aw;
    float v = (lane < NS) ? slog[lane] : -INFINITY;
    float m = wave_reduce_max(v);
    float e = (lane < NS) ? __expf(v - m) : 0.f;
    float s = wave_reduce_sum(e);
    if (lane < NS) wlsT[(l * NS + lane) * B + b] = (e / s) * aw;
    if (lane == 0) a_words[bl] = aw;
  }
}

// ---------------------------------------------------------------------------
// K2: weighted_c[b,s] = sum_l wlsT[l][s][b]; a_slots = wc / sum_l a_words.
// ---------------------------------------------------------------------------
__global__ __launch_bounds__(64) void k2_slots_agg(
    const float* __restrict__ wlsT, const float* __restrict__ a_words,
    float* __restrict__ weighted_c, float* __restrict__ a_slots) {
  int b = blockIdx.x;
  int lane = threadIdx.x;
  float aw = a_words[b * L + lane];
  float sa = wave_reduce_sum(aw);
  if (lane < NS) {
    float wc = 0.f;
    for (int l = 0; l < L; ++l) wc += wlsT[(l * NS + lane) * B + b];
    weighted_c[b * NS + lane] = wc;
    a_slots[b * NS + lane] = wc / sa;
  }
}

// ---------------------------------------------------------------------------
// K3 v10: round-10 skeleton (all-DMA loop, exact vmcnt(9), dbuf, W-once) +
// (a) 32x32x16 MFMA, (b) 2x2 wave grid (wave = 64b x 64i) -> A LDS reads
// halved (2x sharing vs 4x), MFMA count halved, (c) conflict-free A swizzle.
// Per step per wave: 9 DMA (A-hi 2, A-lo 2, W 4, sw 1); vmcnt(9) keeps the
// next step's 9 in flight; NO compiler-visible VMEM in the loop (the round-13
// race lesson).  3-term emulated fp32: Ah*Wh + Ah*Wl + Al*Wh; per-l fold
// R += sw[b]*P in fp32.  LDS 66KB -> 2 blocks/CU.
// ---------------------------------------------------------------------------
__global__ __launch_bounds__(256, 2) void k3_mfma(
    const ushort* __restrict__ xh, const ushort* __restrict__ xl,
    const float* __restrict__ wp, const float* __restrict__ wlsT,
    float* __restrict__ part, int nsplit) {
  __shared__ ushort Ah[2][4096], Al[2][4096];  // dbuf [128 b][32 k] swz, 8KB
  __shared__ float  Wt[2][4096];               // dbuf [128 r][32 k] f32 swz
  __shared__ float  swl[2][256];               // per-l scales (dbuf)

  int bx  = blockIdx.x;
  int sp  = bx & (nsplit - 1);   // bx%nsplit -> same-sp on same XCD
  int rem = bx / nsplit;
  int ih  = rem & 1, s = rem >> 1;
  int i0  = ih * 128;
  int lchunk = L / nsplit, l0 = sp * lchunk;
  int steps  = lchunk * 8;

  int t = threadIdx.x, lane = t & 63, wv = t >> 6;
  int wm = wv >> 1, wn = wv & 1;   // 2x2 wave grid
  int c31 = lane & 31, q2 = lane >> 5;

  f32x16 P[2][2], R[2][2];
#pragma unroll
  for (int mt = 0; mt < 2; ++mt)
#pragma unroll
    for (int nt = 0; nt < 2; ++nt) { P[mt][nt] = (f32x16)0.f; R[mt][nt] = (f32x16)0.f; }

  auto issue = [&](int tn) {       // exactly 9 DMA per wave
    int pb = tn & 1;               // buffer from UNCLAMPED index
    int cs = tn < steps ? tn : steps - 1;
    int li = cs >> 3, jci = cs & 7;
    int l  = l0 + li;
    const ushort* th = xh + ((size_t)l * 8 + jci) * 4096;
    const ushort* tl = xl + ((size_t)l * 8 + jci) * 4096;
    dma16(th + wv * 1024 + lane * 8,       &Ah[pb][wv * 1024]);
    dma16(th + wv * 1024 + 512 + lane * 8, &Ah[pb][wv * 1024 + 512]);
    dma16(tl + wv * 1024 + lane * 8,       &Al[pb][wv * 1024]);
    dma16(tl + wv * 1024 + 512 + lane * 8, &Al[pb][wv * 1024 + 512]);
    const char* wb = (const char*)wp +
                     (((size_t)l * NS + s) * (D * D) + (size_t)i0 * D) * 4 +
                     jci * 128;
    int wrow8 = lane >> 3, wu = lane & 7;
    int wswz  = ((wu ^ wrow8) << 4);
#pragma unroll
    for (int wi = 0; wi < 4; ++wi) {
      int rbase = wv * 32 + wi * 8;
      dma16(wb + (size_t)(rbase + wrow8) * 1024 + wswz,
            (char*)&Wt[pb][0] + rbase * 128);
    }
    const char* sws = (const char*)(wlsT + ((size_t)l * NS + s) * B);
    dma16(sws + lane * 16, &swl[(cs >> 3) & 1][0]);
  };

  issue(0);
  for (int tt = 0; tt < steps; ++tt) {
    issue(tt + 1);
    asm volatile("s_waitcnt vmcnt(9)" ::: "memory");  // step tt landed; tt+1 in flight
    __builtin_amdgcn_s_barrier();
    int pb = tt & 1;
    // ---- W fragments: LDS f32 (swizzled) -> regs -> hi/lo bf16 ----
    bf16x8 wh[2][2], wlo[2][2];    // [nt][kh]
#pragma unroll
    for (int nt = 0; nt < 2; ++nt) {
      int wr = wn * 64 + nt * 32 + c31;
      const char* rb = (const char*)&Wt[pb][0] + wr * 128;
      int key = wr & 7;
#pragma unroll
      for (int kh = 0; kh < 2; ++kh) {
        int u0 = kh * 4 + q2 * 2;
        float4 w0 = *(const float4*)(rb + (((u0    ) ^ key) << 4));
        float4 w1 = *(const float4*)(rb + (((u0 + 1) ^ key) << 4));
        uint2 h0, e0, h1, e1;
        split4(w0, h0, e0);
        split4(w1, h1, e1);
        uint4 hu = {h0.x, h0.y, h1.x, h1.y};
        uint4 lu = {e0.x, e0.y, e1.x, e1.y};
        wh[nt][kh]  = __builtin_bit_cast(bf16x8, hu);
        wlo[nt][kh] = __builtin_bit_cast(bf16x8, lu);
      }
    }
    // ---- A fragments + MFMA (32x32x16, 3 terms) ----
#pragma unroll
    for (int mt = 0; mt < 2; ++mt) {
      int ar   = wm * 64 + mt * 32 + c31;
      int akey = (ar >> 1) & 3;
#pragma unroll
      for (int kh = 0; kh < 2; ++kh) {
        int au = ar * 32 + (((kh * 2 + q2) ^ akey) << 3);
        bf16x8 a_h = *(const bf16x8*)&Ah[pb][au];
        bf16x8 a_l = *(const bf16x8*)&Al[pb][au];
#pragma unroll
        for (int nt = 0; nt < 2; ++nt) {
          P[mt][nt] = __builtin_amdgcn_mfma_f32_32x32x16_bf16(a_h, wh[nt][kh],  P[mt][nt], 0, 0, 0);
          P[mt][nt] = __builtin_amdgcn_mfma_f32_32x32x16_bf16(a_h, wlo[nt][kh], P[mt][nt], 0, 0, 0);
          P[mt][nt] = __builtin_amdgcn_mfma_f32_32x32x16_bf16(a_l, wh[nt][kh],  P[mt][nt], 0, 0, 0);
        }
      }
    }
    // ---- per-l fold: R += sw[row] * P (fp32); C row = (r&3)+8*(r>>2)+4*q2
    if ((tt & 7) == 7) {
      int lb = (tt >> 3) & 1;
#pragma unroll
      for (int mt = 0; mt < 2; ++mt) {
        int rbase = wm * 64 + mt * 32 + 4 * q2;
#pragma unroll
        for (int g = 0; g < 4; ++g) {
          f32x4 s4 = *(const f32x4*)&swl[lb][rbase + g * 8];
#pragma unroll
          for (int nt = 0; nt < 2; ++nt)
#pragma unroll
            for (int w = 0; w < 4; ++w) {
              R[mt][nt][g * 4 + w] += s4[w] * P[mt][nt][g * 4 + w];
              P[mt][nt][g * 4 + w] = 0.f;
            }
        }
      }
    }
    asm volatile("s_waitcnt lgkmcnt(0)" ::: "memory");  // all LDS reads done
    __builtin_amdgcn_s_barrier();                       // before buf overwrite
  }

  // ---- epilogue: write partials ----
  float* pout = part + ((size_t)sp * NS + s) * (B * D);
#pragma unroll
  for (int mt = 0; mt < 2; ++mt)
#pragma unroll
    for (int nt = 0; nt < 2; ++nt) {
      int col = i0 + wn * 64 + nt * 32 + c31;
#pragma unroll
      for (int r = 0; r < 16; ++r) {
        int row = wm * 64 + mt * 32 + (r & 3) + 8 * (r >> 2) + 4 * q2;
        pout[(size_t)row * D + col] = R[mt][nt][r];
      }
    }
}

// ---------------------------------------------------------------------------
// K3R: u_slots[b,s,i] = (sum_sp part[sp,s,b,i]) / weighted_c[b,s]
// ---------------------------------------------------------------------------
__global__ __launch_bounds__(256) void k3r_reduce(
    const float* __restrict__ part, const float* __restrict__ wc,
    float* __restrict__ u_slots, int nsplit) {
  int idx = blockIdx.x * 256 + threadIdx.x;  // over (s,b,i)
  int i  = idx & (D - 1);
  int sb = idx >> 8;
  int b  = sb & (B - 1);
  int s  = sb >> 7;
  float v = 0.f;
  for (int sp = 0; sp < nsplit; ++sp)
    v += part[(size_t)sp * (NS * B * D) + idx];
  u_slots[((size_t)b * NS + s) * D + i] = v / wc[b * NS + s];
}

// ---------------------------------------------------------------------------
// K4: per (b,s): logits2 = w_route_si[s] . u_slots[b,s]; softmax over NI;
//     w2 = c_si * a_slots.
// ---------------------------------------------------------------------------
__global__ __launch_bounds__(64) void k4_route_si(
    const float* __restrict__ u_slots, const float* __restrict__ wr_si,
    const float* __restrict__ a_slots, float* __restrict__ w2) {
  int bs = blockIdx.x;
  int s  = bs & (NS - 1);
  int lane = threadIdx.x;
  __shared__ float su[D];
  __shared__ float slog[NI];
#pragma unroll
  for (int jj = 0; jj < 4; ++jj) su[lane + jj * 64] = u_slots[bs * D + lane + jj * 64];
  __syncthreads();
  for (int i = 0; i < NI; ++i) {
    const float* w = wr_si + (s * NI + i) * D;
    float p = 0.f;
#pragma unroll
    for (int jj = 0; jj < 4; ++jj) {
      int j = lane + jj * 64;
      p = fmaf(w[j], su[j], p);
    }
    p = wave_reduce_sum(p);
    if (lane == 0) slog[i] = p;
  }
  __syncthreads();
  float v = (lane < NI) ? slog[lane] : -INFINITY;
  float m = wave_reduce_max(v);
  float e = (lane < NI) ? __expf(v - m) : 0.f;
  float ssum = wave_reduce_sum(e);
  if (lane < NI) w2[bs * NI + lane] = (e / ssum) * a_slots[bs];
}

// ---------------------------------------------------------------------------
// K5: wc2[b,i] = sum_s w2; a_intents = wc2 / sum_s a_slots.
// ---------------------------------------------------------------------------
__global__ __launch_bounds__(64) void k5_intents_agg(
    const float* __restrict__ w2, const float* __restrict__ a_slots,
    float* __restrict__ wc2, float* __restrict__ a_intents) {
  int b = blockIdx.x;
  int lane = threadIdx.x;
  float as = (lane < NS) ? a_slots[b * NS + lane] : 0.f;
  float sas = wave_reduce_sum(as);
  if (lane < NI) {
    float wc = 0.f;
    for (int s = 0; s < NS; ++s) wc += w2[(b * NS + s) * NI + lane];
    wc2[b * NI + lane] = wc;
    a_intents[b * NI + lane] = wc / sas;
  }
}

// ---------------------------------------------------------------------------
// K6: Wsum[s,i,k] = sum_j w_pose_si[s,i,j,k] (float4-vectorized over k).
// ---------------------------------------------------------------------------
__global__ __launch_bounds__(256) void k6_wsum(
    const float* __restrict__ wps, float* __restrict__ wsum) {
  __shared__ float red[4][D];
  int si = blockIdx.x;
  int t  = threadIdx.x;
  int k4 = (t & 63) * 4;
  int jg = t >> 6;
  const float* base = wps + (size_t)si * D * D;
  float4 acc = {0.f, 0.f, 0.f, 0.f};
  for (int j = jg; j < D; j += 4) {
    float4 v = *(const float4*)(base + (size_t)j * D + k4);
    acc.x += v.x; acc.y += v.y; acc.z += v.z; acc.w += v.w;
  }
  *(float4*)&red[jg][k4] = acc;
  __syncthreads();
  wsum[si * D + t] = (red[0][t] + red[1][t]) + (red[2][t] + red[3][t]);
}

// ---------------------------------------------------------------------------
// K7: u_intents[b,i,k] = sum_s w2[b,s,i]*u_slots[b,s,k]*Wsum[s,i,k] / wc2[b,i]
// ---------------------------------------------------------------------------
__global__ __launch_bounds__(256) void k7_uintents(
    const float* __restrict__ u_slots, const float* __restrict__ w2,
    const float* __restrict__ wsum, const float* __restrict__ wc2,
    float* __restrict__ u_intents) {
  int bi = blockIdx.x;
  int b = bi >> 4, i = bi & (NI - 1);
  int k = threadIdx.x;
  float acc = 0.f;
  for (int s = 0; s < NS; ++s) {
    float w = w2[(b * NS + s) * NI + i];
    acc = fmaf(w * u_slots[(b * NS + s) * D + k], wsum[(s * NI + i) * D + k], acc);
  }
  u_intents[bi * D + k] = acc / wc2[bi];
}

// ---------------------------------------------------------------------------
extern "C" void kernel_launch(void* const* d_in, const int* in_sizes, int n_in,
                              void* d_out, int out_size, void* d_ws, size_t ws_size,
                              hipStream_t stream) {
  const float* tf    = (const float*)d_in[0];  // (B,L,D)
  const float* wr_ws = (const float*)d_in[1];  // (L,NS,D)
  const float* wp_ws = (const float*)d_in[2];  // (L,NS,D,D)
  const float* wr_si = (const float*)d_in[3];  // (NS,NI,D)
  const float* wp_si = (const float*)d_in[4];  // (NS,NI,D,D)

  float* out       = (float*)d_out;
  float* a_slots   = out;                      // B*NS
  float* u_slots   = a_slots + B * NS;         // B*NS*D
  float* a_intents = u_slots + B * NS * D;     // B*NI
  float* u_intents = a_intents + B * NI;       // B*NI*D

  float* ws         = (float*)d_ws;
  float* wlsT       = ws;                      // L*NS*B  = 262144
  float* a_words    = wlsT + L * NS * B;       // B*L     = 8192
  float* weighted_c = a_words + B * L;         // B*NS    = 4096
  float* w2         = weighted_c + B * NS;     // B*NS*NI = 65536
  float* wc2        = w2 + B * NS * NI;        // B*NI    = 2048
  float* wsum       = wc2 + B * NI;            // NS*NI*D = 131072
  // bf16 hi/lo swizzled images of tf: 512 tiles x 4096 ushorts each
  ushort* xh        = (ushort*)(wsum + NS * NI * D);       // 2,097,152 ushorts
  ushort* xl        = xh + (size_t)L * 8 * 4096;           // 2,097,152 ushorts
  float*  part      = (float*)(xl + (size_t)L * 8 * 4096); // nsplit*NS*B*D

  const size_t base_f  = 473088 + 2097152;     // floats incl. images
  const size_t chunk_f = (size_t)NS * B * D;   // 1,048,576 per split
  size_t avail_f = ws_size / sizeof(float);
  int nsplit = 1;
  if (avail_f >= base_f + 8 * chunk_f)      nsplit = 8;
  else if (avail_f >= base_f + 4 * chunk_f) nsplit = 4;
  else if (avail_f >= base_f + 2 * chunk_f) nsplit = 2;

  kx_split<<<L * 4, 256, 0, stream>>>(tf, xh, xl);
  k1_route_words<<<B * L, 256, 0, stream>>>(tf, wr_ws, wlsT, a_words);
  k2_slots_agg<<<B, 64, 0, stream>>>(wlsT, a_words, weighted_c, a_slots);
  // grid: (s x ihalf) x nsplit; bx%nsplit = sp -> same-sp on same XCD
  k3_mfma<<<NS * 2 * nsplit, 256, 0, stream>>>(xh, xl, wp_ws, wlsT, part, nsplit);
  k3r_reduce<<<(NS * B * D) / 256, 256, 0, stream>>>(part, weighted_c, u_slots, nsplit);
  k6_wsum<<<NS * NI, 256, 0, stream>>>(wp_si, wsum);
  k4_route_si<<<B * NS, 64, 0, stream>>>(u_slots, wr_si, a_slots, w2);
  k5_intents_agg<<<B, 64, 0, stream>>>(w2, a_slots, wc2, a_intents);
  k7_uintents<<<B * NI, 256, 0, stream>>>(u_slots, w2, wsum, wc2, u_intents);
}